// Round 15
// baseline (282.756 us; speedup 1.0000x reference)
//
#include <hip/hip_runtime.h>
#include <hip/hip_bf16.h>
#include <cstddef>
#include <cstdint>

#define LN_EPS 0.001f

using short8 = __attribute__((ext_vector_type(8))) short;
using f32x4 = __attribute__((ext_vector_type(4))) float;

#define GLOAD_LDS16(gp, lp)                                                    \
  __builtin_amdgcn_global_load_lds(                                            \
      (const __attribute__((address_space(1))) void*)(gp),                     \
      (__attribute__((address_space(3))) void*)(lp), 16, 0, 0)

static __device__ __forceinline__ short f2bf(float x) {
  __hip_bfloat16 h = __float2bfloat16(x);
  return *reinterpret_cast<short*>(&h);
}

// ------ merged prep: weights + wkr + relb + ln0 + keab/b1t bias-init ------
// 0..6143 weights | 6144..6399 wkr | 6400..6655 relb | 6656..8703 ln0 rows
// 8704..8767 keab init=bab0[h] | 8768..8774 b1t init=bab1[h]
__global__ __launch_bounds__(256) void prep_ln_kernel(
    const float* __restrict__ w_b0, const float* __restrict__ w11,
    const float* __restrict__ wq, const float* __restrict__ wke,
    const float* __restrict__ wkv, const float* __restrict__ w12,
    const float* __restrict__ wkr, const float* __restrict__ rel_enc,
    __hip_bfloat16* __restrict__ w_b0t, __hip_bfloat16* __restrict__ w11t,
    __hip_bfloat16* __restrict__ wqt, __hip_bfloat16* __restrict__ wket,
    __hip_bfloat16* __restrict__ wkvt, __hip_bfloat16* __restrict__ w12t,
    __hip_bfloat16* __restrict__ wkrt, __hip_bfloat16* __restrict__ relb,
    const float* __restrict__ lnx, const float* __restrict__ lng,
    const float* __restrict__ lnb, __hip_bfloat16* __restrict__ lnout,
    const float* __restrict__ bab0, const float* __restrict__ bab1,
    float* __restrict__ keab, float* __restrict__ b1t) {
  int bid = blockIdx.x;
  int t = threadIdx.x;
  if (bid >= 8768) {
    int idx = (bid - 8768) * 256 + t;
    if (idx < 208 * 8) b1t[idx] = bab1[idx & 7];
    return;
  }
  if (bid >= 8704) {
    int idx = (bid - 8704) * 256 + t;   // < 16384
    keab[idx] = bab0[(idx >> 9) & 7];
    return;
  }
  if (bid >= 6656) {
    int row = bid - 6656;
    const float* xr = lnx + (size_t)row * 512;
    float v0 = xr[t], v1 = xr[t + 256];
    float s = v0 + v1, sq = v0 * v0 + v1 * v1;
#pragma unroll
    for (int o = 32; o; o >>= 1) {
      s += __shfl_down(s, o);
      sq += __shfl_down(sq, o);
    }
    __shared__ float wsum[4], wsq[4];
    __shared__ float mean_s, scale_s;
    int wid = t >> 6, lane = t & 63;
    if (lane == 0) { wsum[wid] = s; wsq[wid] = sq; }
    __syncthreads();
    if (t == 0) {
      float S = wsum[0] + wsum[1] + wsum[2] + wsum[3];
      float SQ = wsq[0] + wsq[1] + wsq[2] + wsq[3];
      float mean = S * (1.f / 512.f);
      float var = SQ * (1.f / 512.f) - mean * mean;
      mean_s = mean;
      scale_s = rsqrtf(var + LN_EPS);
    }
    __syncthreads();
    float mean = mean_s, scale = scale_s;
    __hip_bfloat16* orow = lnout + (size_t)row * 512;
    orow[t] = __float2bfloat16((v0 - mean) * scale * lng[t] + lnb[t]);
    orow[t + 256] = __float2bfloat16((v1 - mean) * scale * lng[t + 256] + lnb[t + 256]);
    return;
  }
  if (bid >= 6400) {
    int row = bid - 6400;
    float v0 = 0.f, v1 = 0.f;
    if (row < 201) {
      v0 = rel_enc[(size_t)row * 512 + t];
      v1 = rel_enc[(size_t)row * 512 + t + 256];
    }
    relb[(size_t)row * 512 + t] = __float2bfloat16(v0);
    relb[(size_t)row * 512 + t + 256] = __float2bfloat16(v1);
    return;
  }
  const float* in;
  __hip_bfloat16* outp;
  int R, C, bx, by;
  if (bid < 6144) {
    int seg = bid >> 10, idx = bid & 1023;
    if (seg == 0)      { in = w_b0; outp = w_b0t; R = 512;  C = 2048; }
    else if (seg == 1) { in = w11;  outp = w11t;  R = 512;  C = 2048; }
    else if (seg == 2) { in = wq;   outp = wqt;   R = 2048; C = 512;  }
    else if (seg == 3) { in = wke;  outp = wket;  R = 2048; C = 512;  }
    else if (seg == 4) { in = wkv;  outp = wkvt;  R = 2048; C = 512;  }
    else               { in = w12;  outp = w12t;  R = 2048; C = 512;  }
    if (R == 512) { bx = idx & 63; by = idx >> 6; }
    else          { bx = idx & 15; by = idx >> 4; }
  } else {
    int idx = bid - 6144;
    in = wkr; outp = wkrt; R = 512; C = 512;
    bx = idx & 15; by = idx >> 4;
  }
  __shared__ float tile[32][33];
  int c0 = bx * 32, r0 = by * 32;
  int tx = t & 31, ty = t >> 5;
#pragma unroll
  for (int p = 0; p < 4; p++) {
    int r = ty + p * 8;
    tile[r][tx] = in[(size_t)(r0 + r) * C + c0 + tx];
  }
  __syncthreads();
#pragma unroll
  for (int p = 0; p < 4; p++) {
    int r = ty + p * 8;
    outp[(size_t)(c0 + r) * R + r0 + tx] = __float2bfloat16(tile[tx][r]);
  }
}

// ---------------- plain LayerNorm (for ln1) ----------------
__global__ __launch_bounds__(256) void ln_kernel(const float* __restrict__ x,
                                                 const float* __restrict__ g,
                                                 const float* __restrict__ bb,
                                                 __hip_bfloat16* __restrict__ out) {
  int row = blockIdx.x;
  const float* xr = x + (size_t)row * 512;
  int t = threadIdx.x;
  float v0 = xr[t], v1 = xr[t + 256];
  float s = v0 + v1, sq = v0 * v0 + v1 * v1;
#pragma unroll
  for (int o = 32; o; o >>= 1) {
    s += __shfl_down(s, o);
    sq += __shfl_down(sq, o);
  }
  __shared__ float wsum[4], wsq[4];
  __shared__ float mean_s, scale_s;
  int wid = t >> 6, lane = t & 63;
  if (lane == 0) { wsum[wid] = s; wsq[wid] = sq; }
  __syncthreads();
  if (t == 0) {
    float S = wsum[0] + wsum[1] + wsum[2] + wsum[3];
    float SQ = wsq[0] + wsq[1] + wsq[2] + wsq[3];
    float mean = S * (1.f / 512.f);
    float var = SQ * (1.f / 512.f) - mean * mean;
    mean_s = mean;
    scale_s = rsqrtf(var + LN_EPS);
  }
  __syncthreads();
  float mean = mean_s, scale = scale_s;
  __hip_bfloat16* orow = out + (size_t)row * 512;
  orow[t] = __float2bfloat16((v0 - mean) * scale * g[t] + bb[t]);
  orow[t + 256] = __float2bfloat16((v1 - mean) * scale * g[t + 256] + bb[t + 256]);
}

// ---- bf16 MFMA GEMM, TMxTN, BK=64, XOR swizzle, dbuf LDS, fused epilogue dots --
// MODE 0: fp32 out (+resid). MODE 1: bf16 out (+folded kr problem via ysplit).
// MODE 2: q|ke|kvt split bf16 (kvt stores packed 8B).
// DOT=1: seg-1 (ke) blocks accumulate keab[b,h,s] via wdot0 (all 8 heads);
//        is_kr blocks accumulate b1t[r,h] via wdot1. Targets bias-initialized.
template <int TM, int TN, int MODE, int RELU, int RESID, int DOT>
__global__ __launch_bounds__(256) void gemm_mfma(
    const __hip_bfloat16* __restrict__ A, const __hip_bfloat16* __restrict__ Bt,
    const float* __restrict__ bias0, const float* __restrict__ bias1,
    const float* __restrict__ bias2, const float* __restrict__ resid,
    void* __restrict__ out0, void* __restrict__ out1, void* __restrict__ out2,
    int M, int N, int K,
    const __hip_bfloat16* A2, const __hip_bfloat16* B2t,
    const float* bias_kr, void* out_kr, int ysplit,
    const float* wdot0, float* dot0, const float* wdot1, float* dot1) {
  constexpr int FM = TM / 32;
  constexpr int FN = TN / 32;
  __shared__ short As[2][TM * 64];
  __shared__ short Bs[2][TN * 64];
  int tid = threadIdx.x;
  int w = tid >> 6, lane = tid & 63;
  int wrow = (w >> 1) * (TM / 2);
  int wcol = (w & 1) * (TN / 2);
  int quad = lane >> 4, l16 = lane & 15;
  int bx = blockIdx.x, by = blockIdx.y;
  const short* Ag = (const short*)A;
  const short* Bg = (const short*)Bt;
  int N_ = N, K_ = K;
  bool is_kr = false;
  if (MODE == 1 && ysplit > 0 && by >= ysplit) {
    if (bx >= 512 / TN) return;   // kr problem has N=512
    is_kr = true;
    by -= ysplit;
    Ag = (const short*)A2;
    Bg = (const short*)B2t;
    N_ = 512;
    K_ = 512;
  }
  int row0 = by * TM, col0 = bx * TN;
  f32x4 acc[FM][FN];
#pragma unroll
  for (int i = 0; i < FM; i++)
#pragma unroll
    for (int j = 0; j < FN; j++) acc[i][j] = {0.f, 0.f, 0.f, 0.f};

  auto stage = [&](int k0, int buf) {
#pragma unroll
    for (int p = 0; p < TM / 32; p++) {
      int e = p * 256 + tid;
      int r = e >> 3, sc = e & 7;
      int c = sc ^ (r & 7);
      GLOAD_LDS16(Ag + (size_t)(row0 + r) * K_ + k0 + c * 8, &As[buf][e * 8]);
    }
#pragma unroll
    for (int p = 0; p < TN / 32; p++) {
      int e = p * 256 + tid;
      int r = e >> 3, sc = e & 7;
      int c = sc ^ (r & 7);
      GLOAD_LDS16(Bg + (size_t)(col0 + r) * K_ + k0 + c * 8, &Bs[buf][e * 8]);
    }
  };

  int nIter = K_ >> 6;
  stage(0, 0);
  for (int it = 0; it < nIter; ++it) {
    int cur = it & 1;
    __syncthreads();
    if (it + 1 < nIter) stage((it + 1) << 6, cur ^ 1);
#pragma unroll
    for (int u = 0; u < 2; u++) {
      short8 af[FM], bf[FN];
#pragma unroll
      for (int f = 0; f < FM; f++) {
        int r = wrow + f * 16 + l16;
        int slot = (u * 4 + quad) ^ (r & 7);
        af[f] = *(const short8*)&As[cur][(r * 8 + slot) * 8];
      }
#pragma unroll
      for (int f = 0; f < FN; f++) {
        int r = wcol + f * 16 + l16;
        int slot = (u * 4 + quad) ^ (r & 7);
        bf[f] = *(const short8*)&Bs[cur][(r * 8 + slot) * 8];
      }
#pragma unroll
      for (int fm = 0; fm < FM; fm++)
#pragma unroll
        for (int fn = 0; fn < FN; fn++)
          acc[fm][fn] = __builtin_amdgcn_mfma_f32_16x16x32_bf16(af[fm], bf[fn], acc[fm][fn], 0, 0, 0);
    }
  }

  // ----------------- epilogue -----------------
  if (MODE == 2) {
    int seg = col0 >> 9;
    const float* bp = (seg == 0) ? bias0 : (seg == 1 ? bias1 : bias2);
    if (seg < 2) {
      __hip_bfloat16* dst = (__hip_bfloat16*)(seg == 0 ? out0 : out1);
#pragma unroll
      for (int fm = 0; fm < FM; fm++) {
#pragma unroll
        for (int r = 0; r < 4; r++) {
          int gr = row0 + wrow + fm * 16 + quad * 4 + r;
          float dotp[8] = {0.f, 0.f, 0.f, 0.f, 0.f, 0.f, 0.f, 0.f};
#pragma unroll
          for (int fn = 0; fn < FN; fn++) {
            int gc = col0 + wcol + fn * 16 + l16;
            int bcol = gc - seg * 512;
            float v = acc[fm][fn][r] + bp[bcol];
            dst[(size_t)gr * 512 + bcol] = __float2bfloat16(v);
            if (DOT && seg == 1) {
              const float4* wv = (const float4*)&wdot0[(size_t)bcol * 8];
              float4 w0 = wv[0], w1 = wv[1];
              dotp[0] += v * w0.x; dotp[1] += v * w0.y; dotp[2] += v * w0.z; dotp[3] += v * w0.w;
              dotp[4] += v * w1.x; dotp[5] += v * w1.y; dotp[6] += v * w1.z; dotp[7] += v * w1.w;
            }
          }
          if (DOT && seg == 1) {
#pragma unroll
            for (int h = 0; h < 8; h++) {
              float d = dotp[h];
              d += __shfl_xor(d, 1);
              d += __shfl_xor(d, 2);
              d += __shfl_xor(d, 4);
              d += __shfl_xor(d, 8);
              if (l16 == 0) {
                int b_ = gr >> 9, s_ = gr & 511;
                atomicAdd(&dot0[(size_t)(b_ * 8 + h) * 512 + s_], d);
              }
            }
          }
        }
      }
    } else {
      // kvt[b,h,d,s]: 4 consecutive s per fragment -> one packed 8B store
#pragma unroll
      for (int fm = 0; fm < FM; fm++) {
#pragma unroll
        for (int fn = 0; fn < FN; fn++) {
          int gc = col0 + wcol + fn * 16 + l16;
          int bcol = gc - 1024;
          float bv = bp[bcol];
          int gr0 = row0 + wrow + fm * 16 + quad * 4;
          union { unsigned long long u; short s4[4]; } pk;
#pragma unroll
          for (int r = 0; r < 4; r++) pk.s4[r] = f2bf(acc[fm][fn][r] + bv);
          int b_ = gr0 >> 9, s_ = gr0 & 511;
          int h_ = bcol >> 6, d_ = bcol & 63;
          *(unsigned long long*)&((short*)out2)[(size_t)((b_ * 8 + h_) * 64 + d_) * 512 + s_] = pk.u;
        }
      }
    }
  } else if (MODE == 1) {
    const float* bp = is_kr ? bias_kr : bias0;
    __hip_bfloat16* dst = is_kr ? (__hip_bfloat16*)out_kr : (__hip_bfloat16*)out0;
#pragma unroll
    for (int fm = 0; fm < FM; fm++) {
#pragma unroll
      for (int r = 0; r < 4; r++) {
        int gr = row0 + wrow + fm * 16 + quad * 4 + r;
        float dotp[8] = {0.f, 0.f, 0.f, 0.f, 0.f, 0.f, 0.f, 0.f};
#pragma unroll
        for (int fn = 0; fn < FN; fn++) {
          int gc = col0 + wcol + fn * 16 + l16;
          float v = acc[fm][fn][r] + bp[gc];
          if (RELU && !is_kr) v = fmaxf(v, 0.f);
          dst[(size_t)gr * N_ + gc] = __float2bfloat16(v);
          if (DOT && is_kr) {
            const float4* wv = (const float4*)&wdot1[(size_t)gc * 8];
            float4 w0 = wv[0], w1 = wv[1];
            dotp[0] += v * w0.x; dotp[1] += v * w0.y; dotp[2] += v * w0.z; dotp[3] += v * w0.w;
            dotp[4] += v * w1.x; dotp[5] += v * w1.y; dotp[6] += v * w1.z; dotp[7] += v * w1.w;
          }
        }
        if (DOT && is_kr) {
#pragma unroll
          for (int h = 0; h < 8; h++) {
            float d = dotp[h];
            d += __shfl_xor(d, 1);
            d += __shfl_xor(d, 2);
            d += __shfl_xor(d, 4);
            d += __shfl_xor(d, 8);
            if (l16 == 0 && gr < 208) atomicAdd(&dot1[gr * 8 + h], d);
          }
        }
      }
    }
  } else {
#pragma unroll
    for (int fm = 0; fm < FM; fm++) {
#pragma unroll
      for (int fn = 0; fn < FN; fn++) {
        int gc = col0 + wcol + fn * 16 + l16;
        float bv = bias0[gc];
#pragma unroll
        for (int r = 0; r < 4; r++) {
          int gr = row0 + wrow + fm * 16 + quad * 4 + r;
          float v = acc[fm][fn][r] + bv;
          if (RELU) v = fmaxf(v, 0.f);
          size_t idx = (size_t)gr * N_ + gc;
          if (RESID) v += resid[idx];
          ((float*)out0)[idx] = v;
        }
      }
    }
  }
}

// ---------------- MFMA flash attention v4 (round-14, unchanged) ----------------
#define PST 136
__global__ __launch_bounds__(256) void attn_mfma4(
    const __hip_bfloat16* __restrict__ q, const __hip_bfloat16* __restrict__ ke,
    const __hip_bfloat16* __restrict__ kvt, const __hip_bfloat16* __restrict__ krtb,
    const float* __restrict__ keab, const float* __restrict__ b1t,
    const float* __restrict__ values, float* __restrict__ v_out) {
  const int S = 512, E = 512;
  __shared__ float bp[16 * 113];
  __shared__ short P[4][16 * PST];
  __shared__ float ml[4][32];
  int tid = threadIdx.x;
  int wave = tid >> 6, lane = tid & 63;
  int quad = lane >> 4, l16 = lane & 15;
  int band = 31 - blockIdx.x;
  int h = blockIdx.y, b = blockIdx.z;
  int wi0 = band * 16;

  const short* qg = (const short*)q;
  const short* keg = (const short*)ke;
  const short* kvtg = (const short*)kvt;
  const short* krg = (const short*)krtb;

  short8 aq[2];
#pragma unroll
  for (int kk = 0; kk < 2; kk++)
    aq[kk] = *(const short8*)&qg[(size_t)(b * S + wi0 + l16) * E + h * 64 + kk * 32 + quad * 8];

#pragma unroll
  for (int oi = 0; oi < 2; oi++) {
    int on = wave + oi * 4;
    if (on < 7) {
      f32x4 c = {0.f, 0.f, 0.f, 0.f};
#pragma unroll
      for (int kk = 0; kk < 2; kk++) {
        short8 bfr = *(const short8*)&krg[(size_t)(on * 16 + l16) * E + h * 64 + kk * 32 + quad * 8];
        c = __builtin_amdgcn_mfma_f32_16x16x32_bf16(aq[kk], bfr, c, 0, 0, 0);
      }
      float b1 = b1t[(on * 16 + l16) * 8 + h];
#pragma unroll
      for (int rr = 0; rr < 4; rr++)
        bp[(quad * 4 + rr) * 113 + on * 16 + l16] = c[rr] + b1;
    }
  }
  __syncthreads();

  int nb = (band >= wave) ? (((band - wave) >> 2) + 1) : 0;

  f32x4 s[8];
  const float* keabh = keab + (size_t)(b * 8 + h) * 512;
#pragma unroll
  for (int t = 0; t < 8; t++) {
    if (t < nb) {
      int j = (4 * t + wave) * 16 + l16;
      f32x4 c = {0.f, 0.f, 0.f, 0.f};
#pragma unroll
      for (int kk = 0; kk < 2; kk++) {
        short8 bk = *(const short8*)&keg[(size_t)(b * S + j) * E + h * 64 + kk * 32 + quad * 8];
        c = __builtin_amdgcn_mfma_f32_16x16x32_bf16(aq[kk], bk, c, 0, 0, 0);
      }
      float ka = keabh[j];
#pragma unroll
      for (int rr = 0; rr < 4; rr++) {
        int i = wi0 + quad * 4 + rr;
        float val = -1e30f;
        if (j <= i) {
          int off = j - i + 100;
          if (off < 0) off = 0;
          val = c[rr] * 0.125f + bp[(quad * 4 + rr) * 113 + off] + ka;
        }
        s[t][rr] = val;
      }
    }
  }

  float m_r[4] = {-1e30f, -1e30f, -1e30f, -1e30f};
#pragma unroll
  for (int t = 0; t < 8; t++)
    if (t < nb)
#pragma unroll
      for (int rr = 0; rr < 4; rr++) m_r[rr] = fmaxf(m_r[rr], s[t][rr]);
#pragma unroll
  for (int rr = 0; rr < 4; rr++) {
    float v = m_r[rr];
    v = fmaxf(v, __shfl_xor(v, 1));
    v = fmaxf(v, __shfl_xor(v, 2));
    v = fmaxf(v, __shfl_xor(v, 4));
    v = fmaxf(v, __shfl_xor(v, 8));
    m_r[rr] = v;
  }
  float l_r[4] = {0.f, 0.f, 0.f, 0.f};
  short* Pw = &P[wave][0];
#pragma unroll
  for (int t = 0; t < 8; t++) {
    if (t < nb) {
#pragma unroll
      for (int rr = 0; rr < 4; rr++) {
        float p = __expf(s[t][rr] - m_r[rr]);
        l_r[rr] += p;
        Pw[(quad * 4 + rr) * PST + t * 16 + l16] = f2bf(p);
      }
    }
  }
  if (nb & 1) {
#pragma unroll
    for (int rr = 0; rr < 4; rr++)
      Pw[(quad * 4 + rr) * PST + nb * 16 + l16] = 0;
  }
#pragma unroll
  for (int rr = 0; rr < 4; rr++) {
    float v = l_r[rr];
    v += __shfl_xor(v, 1);
    v += __shfl_xor(v, 2);
    v += __shfl_xor(v, 4);
    v += __shfl_xor(v, 8);
    l_r[rr] = v;
  }

  f32x4 o[4] = {{0.f,0.f,0.f,0.f},{0.f,0.f,0.f,0.f},{0.f,0.f,0.f,0.f},{0.f,0.f,0.f,0.f}};
  int nkk = (nb + 1) >> 1;
  const short* kvbase = &kvtg[(size_t)(b * 8 + h) * 64 * S];
#pragma unroll
  for (int kk = 0; kk < 4; kk++) {
    if (kk < nkk) {
      short8 ap = *(const short8*)&Pw[l16 * PST + kk * 32 + quad * 8];
      int jgl = (4 * (2 * kk + (quad >> 1)) + wave) * 16 + (quad & 1) * 8;
#pragma unroll
      for (int dn = 0; dn < 4; dn++) {
        short8 bv = *(const short8*)&kvbase[(size_t)(dn * 16 + l16) * S + jgl];
        o[dn] = __builtin_amdgcn_mfma_f32_16x16x32_bf16(ap, bv, o[dn], 0, 0, 0);
      }
    }
  }

  float* omw = (float*)&P[wave][0];
#pragma unroll
  for (int rr = 0; rr < 4; rr++) {
    int row = quad * 4 + rr;
    if (l16 == 0) {
      ml[wave][row * 2] = m_r[rr];
      ml[wave][row * 2 + 1] = l_r[rr];
    }
#pragma unroll
    for (int dn = 0; dn < 4; dn++)
      omw[row * 68 + dn * 16 + l16] = o[dn][rr];
  }
  __syncthreads();
  int dn = wave;
#pragma unroll
  for (int rr = 0; rr < 4; rr++) {
    int row = quad * 4 + rr;
    float ms = -1e30f;
#pragma unroll
    for (int wv = 0; wv < 4; wv++) ms = fmaxf(ms, ml[wv][row * 2]);
    float lsum = 0.f, oo = 0.f;
    int col = dn * 16 + l16;
#pragma unroll
    for (int wv = 0; wv < 4; wv++) {
      float aw = __expf(ml[wv][row * 2] - ms);
      lsum += ml[wv][row * 2 + 1] * aw;
      oo += ((float*)&P[wv][0])[row * 68 + col] * aw;
    }
    oo /= lsum;
    size_t idx = (size_t)(b * S + wi0 + row) * E + h * 64 + col;
    v_out[idx] = values[idx] + oo;
  }
}

extern "C" void kernel_launch(void* const* d_in, const int* in_sizes, int n_in,
                              void* d_out, int out_size, void* d_ws, size_t ws_size,
                              hipStream_t stream) {
  const float* values = (const float*)d_in[0];
  const float* rel_enc = (const float*)d_in[2];
  const float* ln0_g = (const float*)d_in[3];
  const float* ln0_b = (const float*)d_in[4];
  const float* w_b0 = (const float*)d_in[5];
  const float* b_b0 = (const float*)d_in[6];
  const float* wq = (const float*)d_in[7];
  const float* bq = (const float*)d_in[8];
  const float* wke = (const float*)d_in[9];
  const float* bke = (const float*)d_in[10];
  const float* wkv = (const float*)d_in[11];
  const float* bkv = (const float*)d_in[12];
  const float* wkr = (const float*)d_in[13];
  const float* bkr = (const float*)d_in[14];
  const float* wab0 = (const float*)d_in[15];
  const float* bab0 = (const float*)d_in[16];
  const float* wab1 = (const float*)d_in[17];
  const float* bab1 = (const float*)d_in[18];
  const float* ln1_g = (const float*)d_in[19];
  const float* ln1_b = (const float*)d_in[20];
  const float* w11 = (const float*)d_in[21];
  const float* b11 = (const float*)d_in[22];
  const float* w12 = (const float*)d_in[23];
  const float* b12 = (const float*)d_in[24];
  float* out = (float*)d_out;

  char* p = (char*)d_ws;
  __hip_bfloat16* buf_ln = (__hip_bfloat16*)p;  p += (size_t)2048 * 512 * 2;
  __hip_bfloat16* x      = (__hip_bfloat16*)p;  p += (size_t)2048 * 2048 * 2;
  __hip_bfloat16* q      = (__hip_bfloat16*)p;  p += (size_t)2048 * 512 * 2;
  __hip_bfloat16* ke     = (__hip_bfloat16*)p;  p += (size_t)2048 * 512 * 2;
  __hip_bfloat16* kvt    = (__hip_bfloat16*)p;  p += (size_t)2048 * 512 * 2;
  float* v    = (float*)p;                      p += (size_t)2048 * 512 * 4;
  __hip_bfloat16* krtb = (__hip_bfloat16*)p;    p += (size_t)256 * 512 * 2;
  __hip_bfloat16* relb = (__hip_bfloat16*)p;    p += (size_t)256 * 512 * 2;
  __hip_bfloat16* wkrt = (__hip_bfloat16*)p;    p += (size_t)512 * 512 * 2;
  float* keab = (float*)p;                      p += (size_t)4 * 8 * 512 * 4;
  float* b1t  = (float*)p;                      p += (size_t)208 * 8 * 4;
  __hip_bfloat16* w_b0t = (__hip_bfloat16*)p;   p += (size_t)2048 * 512 * 2;
  __hip_bfloat16* wcatt = (__hip_bfloat16*)p;   p += (size_t)1536 * 2048 * 2;
  __hip_bfloat16* w11t  = (__hip_bfloat16*)p;   p += (size_t)2048 * 512 * 2;
  __hip_bfloat16* w12t  = (__hip_bfloat16*)p;   p += (size_t)512 * 2048 * 2;

  __hip_bfloat16* wqt  = wcatt;
  __hip_bfloat16* wket = wcatt + (size_t)512 * 2048;
  __hip_bfloat16* wkvt = wcatt + (size_t)1024 * 2048;

  // 0. weight prep + ln0 + keab/b1t bias-init
  prep_ln_kernel<<<8775, 256, 0, stream>>>(w_b0, w11, wq, wke, wkv, w12, wkr, rel_enc,
                                           w_b0t, w11t, wqt, wket, wkvt, w12t, wkrt, relb,
                                           values, ln0_g, ln0_b, buf_ln,
                                           bab0, bab1, keab, b1t);
  // 1. x = relu(ln0 @ w_b0 + b_b0) bf16 + folded kr table (+fused b1t)
  gemm_mfma<128, 64, 1, 1, 0, 1><<<dim3(32, 18), 256, 0, stream>>>(
      buf_ln, w_b0t, b_b0, nullptr, nullptr, nullptr, x, nullptr, nullptr,
      2048, 2048, 512, relb, wkrt, bkr, krtb, 16,
      nullptr, nullptr, wab1, b1t);
  // 2. q|ke|kvt = x @ [wq|wke|wkv] + b, bf16 split (+fused keab)
  gemm_mfma<128, 64, 2, 0, 0, 1><<<dim3(24, 16), 256, 0, stream>>>(
      x, wcatt, bq, bke, bkv, nullptr, q, ke, kvt, 2048, 1536, 2048,
      nullptr, nullptr, nullptr, nullptr, 0,
      wab0, keab, nullptr, nullptr);
  // 3. MFMA flash attention -> v = values + att
  attn_mfma4<<<dim3(32, 8, 4), 256, 0, stream>>>(q, ke, kvt, krtb, keab, b1t, values, v);
  // 4. ln1 -> bf16
  ln_kernel<<<2048, 256, 0, stream>>>(v, ln1_g, ln1_b, buf_ln);
  // 5. h1 = relu(ln1 @ w11 + b11), bf16
  gemm_mfma<128, 64, 1, 1, 0, 0><<<dim3(32, 16), 256, 0, stream>>>(
      buf_ln, w11t, b11, nullptr, nullptr, nullptr, x, nullptr, nullptr,
      2048, 2048, 512, nullptr, nullptr, nullptr, nullptr, 0,
      nullptr, nullptr, nullptr, nullptr);
  // 6. out = v + h1 @ w12 + b12
  gemm_mfma<64, 64, 0, 0, 1, 0><<<dim3(8, 32), 256, 0, stream>>>(
      x, w12t, b12, nullptr, nullptr, v, out, nullptr, nullptr, 2048, 512, 2048,
      nullptr, nullptr, nullptr, nullptr, 0,
      nullptr, nullptr, nullptr, nullptr);
}

// Round 16
// 225.590 us; speedup vs baseline: 1.2534x; 1.2534x over previous
//
#include <hip/hip_runtime.h>
#include <hip/hip_bf16.h>
#include <cstddef>
#include <cstdint>

#define LN_EPS 0.001f

using short8 = __attribute__((ext_vector_type(8))) short;
using f32x4 = __attribute__((ext_vector_type(4))) float;

#define GLOAD_LDS16(gp, lp)                                                    \
  __builtin_amdgcn_global_load_lds(                                            \
      (const __attribute__((address_space(1))) void*)(gp),                     \
      (__attribute__((address_space(3))) void*)(lp), 16, 0, 0)

static __device__ __forceinline__ short f2bf(float x) {
  __hip_bfloat16 h = __float2bfloat16(x);
  return *reinterpret_cast<short*>(&h);
}

// ---------------- merged prep (weights) + ln0: one launch ----------------
__global__ __launch_bounds__(256) void prep_ln_kernel(
    const float* __restrict__ w_b0, const float* __restrict__ w11,
    const float* __restrict__ wq, const float* __restrict__ wke,
    const float* __restrict__ wkv, const float* __restrict__ w12,
    const float* __restrict__ wkr, const float* __restrict__ rel_enc,
    __hip_bfloat16* __restrict__ w_b0t, __hip_bfloat16* __restrict__ w11t,
    __hip_bfloat16* __restrict__ wqt, __hip_bfloat16* __restrict__ wket,
    __hip_bfloat16* __restrict__ wkvt, __hip_bfloat16* __restrict__ w12t,
    __hip_bfloat16* __restrict__ wkrt, __hip_bfloat16* __restrict__ relb,
    const float* __restrict__ lnx, const float* __restrict__ lng,
    const float* __restrict__ lnb, __hip_bfloat16* __restrict__ lnout) {
  int bid = blockIdx.x;
  int t = threadIdx.x;
  if (bid >= 6656) {
    int row = bid - 6656;
    const float* xr = lnx + (size_t)row * 512;
    float v0 = xr[t], v1 = xr[t + 256];
    float s = v0 + v1, sq = v0 * v0 + v1 * v1;
#pragma unroll
    for (int o = 32; o; o >>= 1) {
      s += __shfl_down(s, o);
      sq += __shfl_down(sq, o);
    }
    __shared__ float wsum[4], wsq[4];
    __shared__ float mean_s, scale_s;
    int wid = t >> 6, lane = t & 63;
    if (lane == 0) { wsum[wid] = s; wsq[wid] = sq; }
    __syncthreads();
    if (t == 0) {
      float S = wsum[0] + wsum[1] + wsum[2] + wsum[3];
      float SQ = wsq[0] + wsq[1] + wsq[2] + wsq[3];
      float mean = S * (1.f / 512.f);
      float var = SQ * (1.f / 512.f) - mean * mean;
      mean_s = mean;
      scale_s = rsqrtf(var + LN_EPS);
    }
    __syncthreads();
    float mean = mean_s, scale = scale_s;
    __hip_bfloat16* orow = lnout + (size_t)row * 512;
    orow[t] = __float2bfloat16((v0 - mean) * scale * lng[t] + lnb[t]);
    orow[t + 256] = __float2bfloat16((v1 - mean) * scale * lng[t + 256] + lnb[t + 256]);
    return;
  }
  if (bid >= 6400) {
    int row = bid - 6400;
    float v0 = 0.f, v1 = 0.f;
    if (row < 201) {
      v0 = rel_enc[(size_t)row * 512 + t];
      v1 = rel_enc[(size_t)row * 512 + t + 256];
    }
    relb[(size_t)row * 512 + t] = __float2bfloat16(v0);
    relb[(size_t)row * 512 + t + 256] = __float2bfloat16(v1);
    return;
  }
  const float* in;
  __hip_bfloat16* outp;
  int R, C, bx, by;
  if (bid < 6144) {
    int seg = bid >> 10, idx = bid & 1023;
    if (seg == 0)      { in = w_b0; outp = w_b0t; R = 512;  C = 2048; }
    else if (seg == 1) { in = w11;  outp = w11t;  R = 512;  C = 2048; }
    else if (seg == 2) { in = wq;   outp = wqt;   R = 2048; C = 512;  }
    else if (seg == 3) { in = wke;  outp = wket;  R = 2048; C = 512;  }
    else if (seg == 4) { in = wkv;  outp = wkvt;  R = 2048; C = 512;  }
    else               { in = w12;  outp = w12t;  R = 2048; C = 512;  }
    if (R == 512) { bx = idx & 63; by = idx >> 6; }
    else          { bx = idx & 15; by = idx >> 4; }
  } else {
    int idx = bid - 6144;
    in = wkr; outp = wkrt; R = 512; C = 512;
    bx = idx & 15; by = idx >> 4;
  }
  __shared__ float tile[32][33];
  int c0 = bx * 32, r0 = by * 32;
  int tx = t & 31, ty = t >> 5;
#pragma unroll
  for (int p = 0; p < 4; p++) {
    int r = ty + p * 8;
    tile[r][tx] = in[(size_t)(r0 + r) * C + c0 + tx];
  }
  __syncthreads();
#pragma unroll
  for (int p = 0; p < 4; p++) {
    int r = ty + p * 8;
    outp[(size_t)(c0 + r) * R + r0 + tx] = __float2bfloat16(tile[tx][r]);
  }
}

// ---------------- plain LayerNorm (for ln1) ----------------
__global__ __launch_bounds__(256) void ln_kernel(const float* __restrict__ x,
                                                 const float* __restrict__ g,
                                                 const float* __restrict__ bb,
                                                 __hip_bfloat16* __restrict__ out) {
  int row = blockIdx.x;
  const float* xr = x + (size_t)row * 512;
  int t = threadIdx.x;
  float v0 = xr[t], v1 = xr[t + 256];
  float s = v0 + v1, sq = v0 * v0 + v1 * v1;
#pragma unroll
  for (int o = 32; o; o >>= 1) {
    s += __shfl_down(s, o);
    sq += __shfl_down(sq, o);
  }
  __shared__ float wsum[4], wsq[4];
  __shared__ float mean_s, scale_s;
  int wid = t >> 6, lane = t & 63;
  if (lane == 0) { wsum[wid] = s; wsq[wid] = sq; }
  __syncthreads();
  if (t == 0) {
    float S = wsum[0] + wsum[1] + wsum[2] + wsum[3];
    float SQ = wsq[0] + wsq[1] + wsq[2] + wsq[3];
    float mean = S * (1.f / 512.f);
    float var = SQ * (1.f / 512.f) - mean * mean;
    mean_s = mean;
    scale_s = rsqrtf(var + LN_EPS);
  }
  __syncthreads();
  float mean = mean_s, scale = scale_s;
  __hip_bfloat16* orow = out + (size_t)row * 512;
  orow[t] = __float2bfloat16((v0 - mean) * scale * g[t] + bb[t]);
  orow[t + 256] = __float2bfloat16((v1 - mean) * scale * g[t + 256] + bb[t + 256]);
}

// ---- bf16 MFMA GEMM, tile TM x TN, BK=64, XOR swizzle, DOUBLE-BUFFERED LDS ----
// MODE 0: fp32 out (+resid). MODE 1: bf16 out. MODE 2: q|ke|kvt split bf16.
// MODE==1 + ysplit>0: blocks with blockIdx.y >= ysplit run a SECOND problem
// (A2 @ B2t^T + bias_kr -> out_kr bf16, M=256/N=512/K=512, no relu).
template <int TM, int TN, int MODE, int RELU, int RESID>
__global__ __launch_bounds__(256) void gemm_mfma(
    const __hip_bfloat16* __restrict__ A, const __hip_bfloat16* __restrict__ Bt,
    const float* __restrict__ bias0, const float* __restrict__ bias1,
    const float* __restrict__ bias2, const float* __restrict__ resid,
    void* __restrict__ out0, void* __restrict__ out1, void* __restrict__ out2,
    int M, int N, int K,
    const __hip_bfloat16* A2, const __hip_bfloat16* B2t,
    const float* bias_kr, void* out_kr, int ysplit) {
  constexpr int FM = TM / 32;
  constexpr int FN = TN / 32;
  __shared__ short As[2][TM * 64];
  __shared__ short Bs[2][TN * 64];
  int tid = threadIdx.x;
  int w = tid >> 6, lane = tid & 63;
  int wrow = (w >> 1) * (TM / 2);
  int wcol = (w & 1) * (TN / 2);
  int quad = lane >> 4, l16 = lane & 15;
  int bx = blockIdx.x, by = blockIdx.y;
  const short* Ag = (const short*)A;
  const short* Bg = (const short*)Bt;
  int N_ = N, K_ = K;
  bool is_kr = false;
  if (MODE == 1 && ysplit > 0 && by >= ysplit) {
    if (bx >= 512 / TN) return;   // kr problem has N=512
    is_kr = true;
    by -= ysplit;
    Ag = (const short*)A2;
    Bg = (const short*)B2t;
    N_ = 512;
    K_ = 512;
  }
  int row0 = by * TM, col0 = bx * TN;
  f32x4 acc[FM][FN];
#pragma unroll
  for (int i = 0; i < FM; i++)
#pragma unroll
    for (int j = 0; j < FN; j++) acc[i][j] = {0.f, 0.f, 0.f, 0.f};

  auto stage = [&](int k0, int buf) {
#pragma unroll
    for (int p = 0; p < TM / 32; p++) {
      int e = p * 256 + tid;
      int r = e >> 3, sc = e & 7;
      int c = sc ^ (r & 7);
      GLOAD_LDS16(Ag + (size_t)(row0 + r) * K_ + k0 + c * 8, &As[buf][e * 8]);
    }
#pragma unroll
    for (int p = 0; p < TN / 32; p++) {
      int e = p * 256 + tid;
      int r = e >> 3, sc = e & 7;
      int c = sc ^ (r & 7);
      GLOAD_LDS16(Bg + (size_t)(col0 + r) * K_ + k0 + c * 8, &Bs[buf][e * 8]);
    }
  };

  int nIter = K_ >> 6;
  stage(0, 0);
  for (int it = 0; it < nIter; ++it) {
    int cur = it & 1;
    __syncthreads();                       // tile `it` staged; prev compute done
    if (it + 1 < nIter) stage((it + 1) << 6, cur ^ 1);  // async prefetch
#pragma unroll
    for (int u = 0; u < 2; u++) {
      short8 af[FM], bf[FN];
#pragma unroll
      for (int f = 0; f < FM; f++) {
        int r = wrow + f * 16 + l16;
        int slot = (u * 4 + quad) ^ (r & 7);
        af[f] = *(const short8*)&As[cur][(r * 8 + slot) * 8];
      }
#pragma unroll
      for (int f = 0; f < FN; f++) {
        int r = wcol + f * 16 + l16;
        int slot = (u * 4 + quad) ^ (r & 7);
        bf[f] = *(const short8*)&Bs[cur][(r * 8 + slot) * 8];
      }
#pragma unroll
      for (int fm = 0; fm < FM; fm++)
#pragma unroll
        for (int fn = 0; fn < FN; fn++)
          acc[fm][fn] = __builtin_amdgcn_mfma_f32_16x16x32_bf16(af[fm], bf[fn], acc[fm][fn], 0, 0, 0);
    }
  }

  int seg = 0;
  const float* bp = is_kr ? bias_kr : bias0;
  __hip_bfloat16* opb = nullptr;
  if (MODE == 2) {
    seg = col0 >> 9;  // 512-boundaries align with tiles (no straddle)
    bp = (seg == 0) ? bias0 : (seg == 1 ? bias1 : bias2);
    opb = (__hip_bfloat16*)((seg == 0) ? out0 : out1);
  }
#pragma unroll
  for (int fm = 0; fm < FM; fm++) {
#pragma unroll
    for (int fn = 0; fn < FN; fn++) {
      int gc = col0 + wcol + fn * 16 + l16;
      int bcol = (MODE == 2) ? (gc - seg * 512) : gc;
      float bv = bp[bcol];
#pragma unroll
      for (int r = 0; r < 4; r++) {
        int gr = row0 + wrow + fm * 16 + quad * 4 + r;
        float v = acc[fm][fn][r] + bv;
        if (RELU && !is_kr) v = fmaxf(v, 0.f);
        if (MODE == 0) {
          size_t idx = (size_t)gr * N_ + gc;
          if (RESID) v += resid[idx];
          ((float*)out0)[idx] = v;
        } else if (MODE == 1) {
          __hip_bfloat16* dst = is_kr ? (__hip_bfloat16*)out_kr : (__hip_bfloat16*)out0;
          dst[(size_t)gr * N_ + gc] = __float2bfloat16(v);
        } else {
          if (seg < 2) {
            opb[(size_t)gr * 512 + bcol] = __float2bfloat16(v);
          } else {
            int b_ = gr >> 9, s_ = gr & 511;
            int h_ = bcol >> 6, d_ = bcol & 63;
            ((__hip_bfloat16*)out2)[(size_t)((b_ * 8 + h_) * 64 + d_) * 512 + s_] =
                __float2bfloat16(v);
          }
        }
      }
    }
  }
}

// ---------------- merged bias-table rowdots (keab + b1t) ----------------
__global__ void rowdot_merged(const __hip_bfloat16* __restrict__ ke,
                              const __hip_bfloat16* __restrict__ krtb,
                              const float* __restrict__ wab0, const float* __restrict__ bab0,
                              const float* __restrict__ wab1, const float* __restrict__ bab1,
                              float* __restrict__ keab, float* __restrict__ b1t) {
  int bid = blockIdx.x;
  int lane = threadIdx.x;
  int second = (bid >= 2048);
  int r = second ? (bid - 2048) : bid;
  const __hip_bfloat16* ar = (second ? krtb : ke) + (size_t)r * 512;
  const float* W = second ? wab1 : wab0;
  const float* bb = second ? bab1 : bab0;
  float a[8];
#pragma unroll
  for (int u = 0; u < 8; u++) a[u] = __bfloat162float(ar[lane + u * 64]);
  float s[8] = {0.f, 0.f, 0.f, 0.f, 0.f, 0.f, 0.f, 0.f};
#pragma unroll
  for (int u = 0; u < 8; u++) {
    int e = lane + u * 64;
    const float4* w4 = (const float4*)&W[(size_t)e * 8];
    float4 w0 = w4[0], w1 = w4[1];
    s[0] += a[u] * w0.x; s[1] += a[u] * w0.y; s[2] += a[u] * w0.z; s[3] += a[u] * w0.w;
    s[4] += a[u] * w1.x; s[5] += a[u] * w1.y; s[6] += a[u] * w1.z; s[7] += a[u] * w1.w;
  }
#pragma unroll
  for (int h = 0; h < 8; h++) {
    float v = s[h];
#pragma unroll
    for (int o = 1; o < 64; o <<= 1) v += __shfl_xor(v, o);
    if (lane == h) {
      if (!second) {
        int b_ = r >> 9, s_ = r & 511;
        keab[(size_t)(b_ * 8 + h) * 512 + s_] = v + bb[h];
      } else {
        b1t[(size_t)r * 8 + h] = v + bb[h];
      }
    }
  }
}

// ---------------- MFMA flash attention v4: bp deduped across waves ----------------
#define PST 136
__global__ __launch_bounds__(256) void attn_mfma4(
    const __hip_bfloat16* __restrict__ q, const __hip_bfloat16* __restrict__ ke,
    const __hip_bfloat16* __restrict__ kvt, const __hip_bfloat16* __restrict__ krtb,
    const float* __restrict__ keab, const float* __restrict__ b1t,
    const float* __restrict__ values, float* __restrict__ v_out) {
  const int S = 512, E = 512;
  __shared__ float bp[16 * 113];
  __shared__ short P[4][16 * PST];
  __shared__ float ml[4][32];
  int tid = threadIdx.x;
  int wave = tid >> 6, lane = tid & 63;
  int quad = lane >> 4, l16 = lane & 15;
  int band = 31 - blockIdx.x;
  int h = blockIdx.y, b = blockIdx.z;
  int wi0 = band * 16;

  const short* qg = (const short*)q;
  const short* keg = (const short*)ke;
  const short* kvtg = (const short*)kvt;
  const short* krg = (const short*)krtb;

  short8 aq[2];
#pragma unroll
  for (int kk = 0; kk < 2; kk++)
    aq[kk] = *(const short8*)&qg[(size_t)(b * S + wi0 + l16) * E + h * 64 + kk * 32 + quad * 8];

  // bp[i][off] = q_i . krh[off] + b1t[off,h] — on-values split across waves:
  // wave w handles on = w and w+4 (7 values total) -> barrier before use.
#pragma unroll
  for (int oi = 0; oi < 2; oi++) {
    int on = wave + oi * 4;
    if (on < 7) {
      f32x4 c = {0.f, 0.f, 0.f, 0.f};
#pragma unroll
      for (int kk = 0; kk < 2; kk++) {
        short8 bfr = *(const short8*)&krg[(size_t)(on * 16 + l16) * E + h * 64 + kk * 32 + quad * 8];
        c = __builtin_amdgcn_mfma_f32_16x16x32_bf16(aq[kk], bfr, c, 0, 0, 0);
      }
      float b1 = b1t[(on * 16 + l16) * 8 + h];
#pragma unroll
      for (int rr = 0; rr < 4; rr++)
        bp[(quad * 4 + rr) * 113 + on * 16 + l16] = c[rr] + b1;
    }
  }
  __syncthreads();

  int nb = (band >= wave) ? (((band - wave) >> 2) + 1) : 0;

  f32x4 s[8];
  const float* keabh = keab + (size_t)(b * 8 + h) * 512;
#pragma unroll
  for (int t = 0; t < 8; t++) {
    if (t < nb) {
      int j = (4 * t + wave) * 16 + l16;
      f32x4 c = {0.f, 0.f, 0.f, 0.f};
#pragma unroll
      for (int kk = 0; kk < 2; kk++) {
        short8 bk = *(const short8*)&keg[(size_t)(b * S + j) * E + h * 64 + kk * 32 + quad * 8];
        c = __builtin_amdgcn_mfma_f32_16x16x32_bf16(aq[kk], bk, c, 0, 0, 0);
      }
      float ka = keabh[j];
#pragma unroll
      for (int rr = 0; rr < 4; rr++) {
        int i = wi0 + quad * 4 + rr;
        float val = -1e30f;
        if (j <= i) {
          int off = j - i + 100;
          if (off < 0) off = 0;
          val = c[rr] * 0.125f + bp[(quad * 4 + rr) * 113 + off] + ka;
        }
        s[t][rr] = val;
      }
    }
  }

  float m_r[4] = {-1e30f, -1e30f, -1e30f, -1e30f};
#pragma unroll
  for (int t = 0; t < 8; t++)
    if (t < nb)
#pragma unroll
      for (int rr = 0; rr < 4; rr++) m_r[rr] = fmaxf(m_r[rr], s[t][rr]);
#pragma unroll
  for (int rr = 0; rr < 4; rr++) {
    float v = m_r[rr];
    v = fmaxf(v, __shfl_xor(v, 1));
    v = fmaxf(v, __shfl_xor(v, 2));
    v = fmaxf(v, __shfl_xor(v, 4));
    v = fmaxf(v, __shfl_xor(v, 8));
    m_r[rr] = v;
  }
  float l_r[4] = {0.f, 0.f, 0.f, 0.f};
  short* Pw = &P[wave][0];
#pragma unroll
  for (int t = 0; t < 8; t++) {
    if (t < nb) {
#pragma unroll
      for (int rr = 0; rr < 4; rr++) {
        float p = __expf(s[t][rr] - m_r[rr]);
        l_r[rr] += p;
        Pw[(quad * 4 + rr) * PST + t * 16 + l16] = f2bf(p);
      }
    }
  }
  if (nb & 1) {
#pragma unroll
    for (int rr = 0; rr < 4; rr++)
      Pw[(quad * 4 + rr) * PST + nb * 16 + l16] = 0;
  }
#pragma unroll
  for (int rr = 0; rr < 4; rr++) {
    float v = l_r[rr];
    v += __shfl_xor(v, 1);
    v += __shfl_xor(v, 2);
    v += __shfl_xor(v, 4);
    v += __shfl_xor(v, 8);
    l_r[rr] = v;
  }

  f32x4 o[4] = {{0.f,0.f,0.f,0.f},{0.f,0.f,0.f,0.f},{0.f,0.f,0.f,0.f},{0.f,0.f,0.f,0.f}};
  int nkk = (nb + 1) >> 1;
  const short* kvbase = &kvtg[(size_t)(b * 8 + h) * 64 * S];
#pragma unroll
  for (int kk = 0; kk < 4; kk++) {
    if (kk < nkk) {
      short8 ap = *(const short8*)&Pw[l16 * PST + kk * 32 + quad * 8];
      int jgl = (4 * (2 * kk + (quad >> 1)) + wave) * 16 + (quad & 1) * 8;
#pragma unroll
      for (int dn = 0; dn < 4; dn++) {
        short8 bv = *(const short8*)&kvbase[(size_t)(dn * 16 + l16) * S + jgl];
        o[dn] = __builtin_amdgcn_mfma_f32_16x16x32_bf16(ap, bv, o[dn], 0, 0, 0);
      }
    }
  }

  float* omw = (float*)&P[wave][0];
#pragma unroll
  for (int rr = 0; rr < 4; rr++) {
    int row = quad * 4 + rr;
    if (l16 == 0) {
      ml[wave][row * 2] = m_r[rr];
      ml[wave][row * 2 + 1] = l_r[rr];
    }
#pragma unroll
    for (int dn = 0; dn < 4; dn++)
      omw[row * 68 + dn * 16 + l16] = o[dn][rr];
  }
  __syncthreads();
  int dn = wave;
#pragma unroll
  for (int rr = 0; rr < 4; rr++) {
    int row = quad * 4 + rr;
    float ms = -1e30f;
#pragma unroll
    for (int wv = 0; wv < 4; wv++) ms = fmaxf(ms, ml[wv][row * 2]);
    float lsum = 0.f, oo = 0.f;
    int col = dn * 16 + l16;
#pragma unroll
    for (int wv = 0; wv < 4; wv++) {
      float aw = __expf(ml[wv][row * 2] - ms);
      lsum += ml[wv][row * 2 + 1] * aw;
      oo += ((float*)&P[wv][0])[row * 68 + col] * aw;
    }
    oo /= lsum;
    size_t idx = (size_t)(b * S + wi0 + row) * E + h * 64 + col;
    v_out[idx] = values[idx] + oo;
  }
}

extern "C" void kernel_launch(void* const* d_in, const int* in_sizes, int n_in,
                              void* d_out, int out_size, void* d_ws, size_t ws_size,
                              hipStream_t stream) {
  const float* values = (const float*)d_in[0];
  const float* rel_enc = (const float*)d_in[2];
  const float* ln0_g = (const float*)d_in[3];
  const float* ln0_b = (const float*)d_in[4];
  const float* w_b0 = (const float*)d_in[5];
  const float* b_b0 = (const float*)d_in[6];
  const float* wq = (const float*)d_in[7];
  const float* bq = (const float*)d_in[8];
  const float* wke = (const float*)d_in[9];
  const float* bke = (const float*)d_in[10];
  const float* wkv = (const float*)d_in[11];
  const float* bkv = (const float*)d_in[12];
  const float* wkr = (const float*)d_in[13];
  const float* bkr = (const float*)d_in[14];
  const float* wab0 = (const float*)d_in[15];
  const float* bab0 = (const float*)d_in[16];
  const float* wab1 = (const float*)d_in[17];
  const float* bab1 = (const float*)d_in[18];
  const float* ln1_g = (const float*)d_in[19];
  const float* ln1_b = (const float*)d_in[20];
  const float* w11 = (const float*)d_in[21];
  const float* b11 = (const float*)d_in[22];
  const float* w12 = (const float*)d_in[23];
  const float* b12 = (const float*)d_in[24];
  float* out = (float*)d_out;

  char* p = (char*)d_ws;
  __hip_bfloat16* buf_ln = (__hip_bfloat16*)p;  p += (size_t)2048 * 512 * 2;
  __hip_bfloat16* x      = (__hip_bfloat16*)p;  p += (size_t)2048 * 2048 * 2;
  __hip_bfloat16* q      = (__hip_bfloat16*)p;  p += (size_t)2048 * 512 * 2;
  __hip_bfloat16* ke     = (__hip_bfloat16*)p;  p += (size_t)2048 * 512 * 2;
  __hip_bfloat16* kvt    = (__hip_bfloat16*)p;  p += (size_t)2048 * 512 * 2;
  float* v    = (float*)p;                      p += (size_t)2048 * 512 * 4;
  __hip_bfloat16* krtb = (__hip_bfloat16*)p;    p += (size_t)256 * 512 * 2;
  __hip_bfloat16* relb = (__hip_bfloat16*)p;    p += (size_t)256 * 512 * 2;
  __hip_bfloat16* wkrt = (__hip_bfloat16*)p;    p += (size_t)512 * 512 * 2;
  float* keab = (float*)p;                      p += (size_t)4 * 8 * 512 * 4;
  float* b1t  = (float*)p;                      p += (size_t)208 * 8 * 4;
  __hip_bfloat16* w_b0t = (__hip_bfloat16*)p;   p += (size_t)2048 * 512 * 2;
  __hip_bfloat16* wcatt = (__hip_bfloat16*)p;   p += (size_t)1536 * 2048 * 2;
  __hip_bfloat16* w11t  = (__hip_bfloat16*)p;   p += (size_t)2048 * 512 * 2;
  __hip_bfloat16* w12t  = (__hip_bfloat16*)p;   p += (size_t)512 * 2048 * 2;

  __hip_bfloat16* wqt  = wcatt;
  __hip_bfloat16* wket = wcatt + (size_t)512 * 2048;
  __hip_bfloat16* wkvt = wcatt + (size_t)1024 * 2048;

  // 0. weight prep + ln0 in one launch
  prep_ln_kernel<<<8704, 256, 0, stream>>>(w_b0, w11, wq, wke, wkv, w12, wkr, rel_enc,
                                           w_b0t, w11t, wqt, wket, wkvt, w12t, wkrt, relb,
                                           values, ln0_g, ln0_b, buf_ln);
  // 1. x = relu(ln0 @ w_b0 + b_b0) bf16 + FOLDED kr table (grid y 16..17)
  gemm_mfma<128, 64, 1, 1, 0><<<dim3(32, 18), 256, 0, stream>>>(
      buf_ln, w_b0t, b_b0, nullptr, nullptr, nullptr, x, nullptr, nullptr,
      2048, 2048, 512, relb, wkrt, bkr, krtb, 16);
  // 2. q|ke|kvt = x @ [wq|wke|wkv] + b, bf16 split (128x64 dbuf, 384 blocks)
  gemm_mfma<128, 64, 2, 0, 0><<<dim3(24, 16), 256, 0, stream>>>(
      x, wcatt, bq, bke, bkv, nullptr, q, ke, kvt, 2048, 1536, 2048,
      nullptr, nullptr, nullptr, nullptr, 0);
  // 3. bias tables (merged)
  rowdot_merged<<<2249, 64, 0, stream>>>(ke, krtb, wab0, bab0, wab1, bab1, keab, b1t);
  // 4. MFMA flash attention -> v = values + att
  attn_mfma4<<<dim3(32, 8, 4), 256, 0, stream>>>(q, ke, kvt, krtb, keab, b1t, values, v);
  // 5. ln1 -> bf16
  ln_kernel<<<2048, 256, 0, stream>>>(v, ln1_g, ln1_b, buf_ln);
  // 6. h1 = relu(ln1 @ w11 + b11), bf16 (128x64 dbuf, 512 blocks)
  gemm_mfma<128, 64, 1, 1, 0><<<dim3(32, 16), 256, 0, stream>>>(
      buf_ln, w11t, b11, nullptr, nullptr, nullptr, x, nullptr, nullptr,
      2048, 2048, 512, nullptr, nullptr, nullptr, nullptr, 0);
  // 7. out = v + h1 @ w12 + b12 (64x64 dbuf, 256 blocks)
  gemm_mfma<64, 64, 0, 0, 1><<<dim3(8, 32), 256, 0, stream>>>(
      x, w12t, b12, nullptr, nullptr, v, out, nullptr, nullptr, 2048, 512, 2048,
      nullptr, nullptr, nullptr, nullptr, 0);
}